// Round 7
// baseline (347.277 us; speedup 1.0000x reference)
//
#include <hip/hip_runtime.h>
#include <math.h>

// CapsuleLayer dynamic routing, MI355X.
// B=4096, L=200, Din=Dout=64, K=8, 3 iterations.
//
// Key identity: low_new = lc @ S never needs materializing.
//   high_pre = W @ (lc@S) = (W@lc) @ S             (hp then tiny projection)
//   delta    = high @ (lc@S)^T = (high@S^T) @ lc^T (hs then row dots)
//
// R6 -> R7: the fused route kernel was stuck at ~154us profiled across 4
// structural rewrites, invariant to occupancy/conflicts/memory source; its
// 6-phase barrier chain couples two lc passes so neither pipelines. Split:
//   k_hp    = softmax + hp + high + hs   (1 lc pass, writes hs[b] 2KB)
//   k_delta = partial[b] = hs[b] . lc[b] (1 lc pass, pure streaming)
// Branch-free fixed-trip loops (W zero-filled to L) remove sl imbalance.
//
// ws layout (floats):
//   Bc[1600] | St[4096] | hs[B*K*64 = 2,097,152] | partial[B*K*L = 6,553,600]
// partial2 [16*K*L] lives in d_out (fully overwritten by the final pass).

#define B_SZ  4096
#define L_SZ  200
#define DINK  64
#define DOUTK 64
#define K_SZ  8

// ---------------------------- init: copy Bc + transpose S into St
__global__ __launch_bounds__(256) void k_init(const float* __restrict__ Bm,
                                              const float* __restrict__ S,
                                              float* __restrict__ Bc,
                                              float* __restrict__ St) {
    int i = blockIdx.x * 256 + threadIdx.x;
    if (i < K_SZ * L_SZ) Bc[i] = Bm[i];
    int j = i - K_SZ * L_SZ;
    if (j >= 0 && j < DINK * DOUTK) {
        int o = j >> 6, ii = j & 63;
        St[j] = S[ii * DOUTK + o];     // St[o][i] = S[i][o]
    }
}

// --------------------- pass 1: softmax -> hp -> high -> hs (one lc pass)
// grid 4096 x 256.  WRITE_OUT=1 (final iter): write squashed high, no hs.
template<int WRITE_OUT>
__global__ __launch_bounds__(256) void k_hp(const float* __restrict__ lc_g,
                                            const int* __restrict__ seq_len,
                                            const float* __restrict__ S_g,
                                            const float* __restrict__ St_g,
                                            const float* __restrict__ Bc,
                                            float* __restrict__ hs_g,
                                            float* __restrict__ out) {
    __shared__ float W_s[K_SZ][L_SZ];      // 6.4 KB exp(B-m), zero-filled to L
    __shared__ float ovl[4 * K_SZ * DINK]; // 8 KB: hp_part[4][8][64], then hx[8][64]
    __shared__ float hp_s[K_SZ][DINK];     // 2 KB
    float (*hp_part)[K_SZ][DINK] = (float (*)[K_SZ][DINK])ovl;
    float (*hx_s)[DINK] = (float (*)[DINK])ovl;

    int t = threadIdx.x;
    int b = blockIdx.x;
    const float2* lc2 = (const float2*)(lc_g + (long)b * (L_SZ * DINK));
    int sl = seq_len[b];
    int k = t >> 5, g = t & 31;            // warp-mapping for softmax/tiny mats
    int w = t >> 6;                        // wave
    int sub = (t >> 5) & 1;                // half-wave
    int p = t & 31;                        // col-pair

    // 1. masked softmax; W zero-filled to L (fixed-trip downstream)
    const float* bk = Bc + k * L_SZ;
    float m = -3.4e38f;
    for (int l = g; l < sl; l += 32) m = fmaxf(m, bk[l]);
    #pragma unroll
    for (int s = 16; s; s >>= 1) m = fmaxf(m, __shfl_xor(m, s, 32));
    float sum = 0.f;
    for (int l = g; l < L_SZ + 24; l += 32) {     // 7 fixed trips covers 200
        if (l < L_SZ) {
            float e = (l < sl) ? __expf(bk[l] - m) : 0.f;
            sum += e;
            W_s[k][l] = e;
        }
    }
    #pragma unroll
    for (int s = 16; s; s >>= 1) sum += __shfl_xor(sum, s, 32);
    float rinv = 1.0f / sum;
    __syncthreads();                        // B1

    // 2. hp partials: fixed 25 trips, branch-free. Half-wave sub owns rows
    //    l = 8j + 2w + sub (all reads valid; W=0 masks l>=sl). Wave reads
    //    512B contiguous per dwordx2 (rows 2w,2w+1 adjacent).
    {
        float2 acc[K_SZ];
        #pragma unroll
        for (int kk = 0; kk < K_SZ; ++kk) acc[kk] = make_float2(0.f, 0.f);
        int l0 = 2 * w + sub;
        const float2* src = lc2 + l0 * 32 + p;
        #pragma unroll 5
        for (int j = 0; j < 25; ++j) {
            float2 v = src[j * 256];        // row l0+8j, cols 2p,2p+1
            int l = l0 + 8 * j;
            #pragma unroll
            for (int kk = 0; kk < K_SZ; ++kk) {
                float wv = W_s[kk][l];      // 2-addr wave broadcast: free
                acc[kk].x += wv * v.x; acc[kk].y += wv * v.y;
            }
        }
        #pragma unroll
        for (int kk = 0; kk < K_SZ; ++kk) {  // fold sub-rows
            acc[kk].x += __shfl_xor(acc[kk].x, 32, 64);
            acc[kk].y += __shfl_xor(acc[kk].y, 32, 64);
        }
        if (sub == 0) {
            #pragma unroll
            for (int kk = 0; kk < K_SZ; ++kk)
                *(float2*)&hp_part[w][kk][2 * p] = acc[kk];
        }
    }
    __syncthreads();                        // B2

    // 3. reduce 4 wave-chunks; fold rinv
    {
        float2 r = make_float2(0.f, 0.f);
        #pragma unroll
        for (int cc = 0; cc < 4; ++cc) {
            float2 q = *(const float2*)&hp_part[cc][k][2 * g];
            r.x += q.x; r.y += q.y;
        }
        *(float2*)&hp_s[k][2 * g] = make_float2(r.x * rinv, r.y * rinv);
    }
    __syncthreads();                        // B3 (overlay anti-hazard)

    // 4. high[k][o] = sum_i hp[k][i]*S[i][o]; squash.  o=2g,2g+1
    float h0 = 0.f, h1 = 0.f;
    {
        const float* sp = S_g + 2 * g;
        #pragma unroll 8
        for (int i = 0; i < DINK; ++i) {
            float pv = hp_s[k][i];                        // LDS broadcast
            float2 sv = *(const float2*)(sp + i * DOUTK); // L1-hot, coalesced
            h0 += pv * sv.x; h1 += pv * sv.y;
        }
        float nn = h0 * h0 + h1 * h1;
        #pragma unroll
        for (int s = 16; s; s >>= 1) nn += __shfl_xor(nn, s, 32);
        float sc = nn / ((1.0f + nn) * sqrtf(nn + 1e-9f));
        h0 *= sc; h1 *= sc;
    }
    if (WRITE_OUT) {
        float2* ob2 = (float2*)(out + (long)b * (K_SZ * DOUTK) + k * DOUTK);
        ob2[g] = make_float2(h0, h1);
        return;
    }
    *(float2*)&hx_s[k][2 * g] = make_float2(h0, h1);
    // hx_s[k][*] consumed by the same wave below: in-order LDS, no barrier

    // 5. hs[k][i] = sum_o high[k][o]*S[i][o] via St; write straight to global
    {
        float s0 = 0.f, s1 = 0.f;
        const float* stp = St_g + 2 * g;
        #pragma unroll 8
        for (int o = 0; o < DOUTK; ++o) {
            float hv = hx_s[k][o];                        // same-wave broadcast
            float2 sv = *(const float2*)(stp + o * DINK); // L1-hot, coalesced
            s0 += hv * sv.x; s1 += hv * sv.y;
        }
        float2* hb2 = (float2*)(hs_g + (long)b * (K_SZ * DINK) + k * DINK);
        hb2[g] = make_float2(s0, s1);       // 256B contiguous per warp
    }
}

// --------------------- pass 2: delta partial (one lc pass, pure streaming)
// grid 4096 x 256; thread t<200 owns row t.
__global__ __launch_bounds__(256) void k_delta(const float* __restrict__ lc_g,
                                               const float* __restrict__ hs_g,
                                               float* __restrict__ partial) {
    __shared__ float hs_s[K_SZ][DINK];     // 2 KB
    int t = threadIdx.x;
    int b = blockIdx.x;
    // stage hs[b]: 256 threads x float2 = 2 KB, coalesced
    ((float2*)hs_s)[t] = ((const float2*)(hs_g + (long)b * (K_SZ * DINK)))[t];
    __syncthreads();

    if (t < L_SZ) {
        const float4* row4 = (const float4*)(lc_g + (long)b * (L_SZ * DINK)
                                             + (long)t * DINK);
        float* pb = partial + (long)b * (K_SZ * L_SZ);
        float acc[K_SZ] = {};
        #pragma unroll 4
        for (int i4 = 0; i4 < 16; ++i4) {
            float4 v = row4[i4];
            #pragma unroll
            for (int kk = 0; kk < K_SZ; ++kk) {
                float4 h = *(const float4*)&hs_s[kk][i4 * 4];  // b128 broadcast
                acc[kk] += v.x * h.x + v.y * h.y + v.z * h.z + v.w * h.w;
            }
        }
        #pragma unroll
        for (int kk = 0; kk < K_SZ; ++kk)
            pb[kk * L_SZ + t] = acc[kk];    // coalesced over t
    }
}

// --------------------------- deterministic two-stage reduce of partials
__global__ __launch_bounds__(256) void k_reduceA(const float* __restrict__ partial,
                                                 float* __restrict__ partial2) {
    __shared__ float red[256];
    int x = blockIdx.x % 50;       // 32-output group
    int y = blockIdx.x / 50;       // 256-batch chunk
    int t = threadIdx.x;
    int i = x * 32 + (t & 31);
    int sub = t >> 5;
    float s = 0.f;
    for (int p = y * 256 + sub; p < (y + 1) * 256; p += 8)
        s += partial[(long)p * (K_SZ * L_SZ) + i];
    red[t] = s;
    __syncthreads();
    for (int step = 4; step >= 1; step >>= 1) {
        if (sub < step) red[t] += red[t + step * 32];
        __syncthreads();
    }
    if (sub == 0) partial2[y * (K_SZ * L_SZ) + i] = red[t];
}

__global__ __launch_bounds__(256) void k_reduceB(const float* __restrict__ partial2,
                                                 float* __restrict__ Bc) {
    int i = blockIdx.x * 256 + threadIdx.x;
    if (i < K_SZ * L_SZ) {
        float s = 0.f;
        #pragma unroll
        for (int y = 0; y < 16; ++y) s += partial2[y * (K_SZ * L_SZ) + i];
        Bc[i] += s;
    }
}

extern "C" void kernel_launch(void* const* d_in, const int* in_sizes, int n_in,
                              void* d_out, int out_size, void* d_ws, size_t ws_size,
                              hipStream_t stream) {
    const float* lc = (const float*)d_in[0];   // [4096,200,64]
    const int*   sl = (const int*)d_in[1];     // [4096,1]
    const float* Bm = (const float*)d_in[2];   // [1,8,200]
    const float* S  = (const float*)d_in[3];   // [64,64]
    float* out = (float*)d_out;                // [4096,8,64]
    float* ws  = (float*)d_ws;

    float* Bc      = ws;                       // 1,600
    float* St      = Bc + 1600;                // 4,096
    float* hs      = St + 4096;                // 2,097,152
    float* partial = hs + (long)B_SZ * K_SZ * DINK;   // 6,553,600
    float* p2      = out;                      // scratch: overwritten by final pass

    k_init<<<23, 256, 0, stream>>>(Bm, S, Bc, St);

    k_hp<0>  <<<B_SZ, 256, 0, stream>>>(lc, sl, S, St, Bc, hs, out);
    k_delta  <<<B_SZ, 256, 0, stream>>>(lc, hs, partial);
    k_reduceA<<<800, 256, 0, stream>>>(partial, p2);
    k_reduceB<<<7, 256, 0, stream>>>(p2, Bc);

    k_hp<0>  <<<B_SZ, 256, 0, stream>>>(lc, sl, S, St, Bc, hs, out);
    k_delta  <<<B_SZ, 256, 0, stream>>>(lc, hs, partial);
    k_reduceA<<<800, 256, 0, stream>>>(partial, p2);
    k_reduceB<<<7, 256, 0, stream>>>(p2, Bc);

    k_hp<1>  <<<B_SZ, 256, 0, stream>>>(lc, sl, S, St, Bc, hs, out);
}

// Round 8
// 340.870 us; speedup vs baseline: 1.0188x; 1.0188x over previous
//
#include <hip/hip_runtime.h>
#include <math.h>

// CapsuleLayer dynamic routing, MI355X.
// B=4096, L=200, Din=Dout=64, K=8, 3 iterations.
//
// Key identity: low_new = lc @ S never needs materializing.
//   high_pre = W @ (lc@S) = (W@lc) @ S             (hp then tiny projection)
//   delta    = high @ (lc@S)^T = (high@S^T) @ lc^T (hs then row dots)
//
// R7 -> R8: k_hp alone was ~130us (= the whole fused cost); waves stall ~95%.
// The one serial structure never removed: the per-block softmax chain gating
// the stream behind a barrier. Hoist it: k_soft precomputes NORMALIZED
// W[B][8][200] (mask + rinv baked in); the route kernel is then
// W-stage (coalesced) -> hp stream -> high/hs -> delta (re-fused; 2nd lc
// pass is cache-hot). No exp/shuffles/seq_len in the hot kernel; 3 barriers.
//
// ws layout (floats):
//   Bc[1600] | St[4096] | W[B*K*L = 6,553,600] | partial[B*K*L = 6,553,600]
// partial2 [16*K*L] lives in d_out (fully overwritten by the final pass).

#define B_SZ  4096
#define L_SZ  200
#define DINK  64
#define DOUTK 64
#define K_SZ  8

// ---------------------------- init: copy Bc + transpose S into St
__global__ __launch_bounds__(256) void k_init(const float* __restrict__ Bm,
                                              const float* __restrict__ S,
                                              float* __restrict__ Bc,
                                              float* __restrict__ St) {
    int i = blockIdx.x * 256 + threadIdx.x;
    if (i < K_SZ * L_SZ) Bc[i] = Bm[i];
    int j = i - K_SZ * L_SZ;
    if (j >= 0 && j < DINK * DOUTK) {
        int o = j >> 6, ii = j & 63;
        St[j] = S[ii * DOUTK + o];     // St[o][i] = S[i][o]
    }
}

// ---------------- softmax pass: W_g[b][k][l] = normalized masked softmax(Bc)
// grid 4096 x 256; warp k owns row k; coalesced float4 store of the block.
__global__ __launch_bounds__(256) void k_soft(const int* __restrict__ seq_len,
                                              const float* __restrict__ Bc,
                                              float* __restrict__ W_g) {
    __shared__ float W_s[K_SZ][L_SZ];      // 6.4 KB
    int t = threadIdx.x;
    int b = blockIdx.x;
    int k = t >> 5, g = t & 31;
    int sl = seq_len[b];

    const float* bk = Bc + k * L_SZ;
    float m = -3.4e38f;
    for (int l = g; l < sl; l += 32) m = fmaxf(m, bk[l]);
    #pragma unroll
    for (int s = 16; s; s >>= 1) m = fmaxf(m, __shfl_xor(m, s, 32));
    float sum = 0.f;
    for (int l = g; l < L_SZ; l += 32) {
        float e = (l < sl) ? __expf(bk[l] - m) : 0.f;
        sum += e;
        W_s[k][l] = e;
    }
    #pragma unroll
    for (int s = 16; s; s >>= 1) sum += __shfl_xor(sum, s, 32);
    float rinv = 1.0f / sum;
    for (int l = g; l < L_SZ; l += 32) W_s[k][l] *= rinv;   // normalize in LDS
    __syncthreads();

    float4* dst = (float4*)(W_g + (long)b * (K_SZ * L_SZ));
    const float4* src = (const float4*)&W_s[0][0];
    for (int j = t; j < (K_SZ * L_SZ) / 4; j += 256) dst[j] = src[j];
}

// ---------------- route: W-stage -> hp stream -> high/hs -> delta (fused)
// grid 4096 x 256.  WRITE_OUT=1 (final iter): write squashed high, stop.
template<int WRITE_OUT>
__global__ __launch_bounds__(256) void k_route2(const float* __restrict__ lc_g,
                                                const float* __restrict__ W_g,
                                                const float* __restrict__ S_g,
                                                const float* __restrict__ St_g,
                                                float* __restrict__ partial,
                                                float* __restrict__ out) {
    __shared__ float W_s[K_SZ][L_SZ];      // 6.4 KB normalized W (zeros past sl)
    __shared__ float ovl[4 * K_SZ * DINK]; // 8 KB: hp_part[4][8][64];
                                           //   then hx = ovl[0..511], hs = ovl[512..1023]
                                           //   (chunk-0/1 rows are same-warp RW -> no barrier)
    __shared__ float hp_s[K_SZ][DINK];     // 2 KB
    float (*hp_part)[K_SZ][DINK] = (float (*)[K_SZ][DINK])ovl;
    float (*hx_s)[DINK] = (float (*)[DINK])ovl;
    float (*hs_s)[DINK] = (float (*)[DINK])(ovl + K_SZ * DINK);

    int t = threadIdx.x;
    int b = blockIdx.x;
    const float* lcb = lc_g + (long)b * (L_SZ * DINK);
    const float2* lc2 = (const float2*)lcb;
    int k = t >> 5, g = t & 31;            // warp-mapping (tiny mats)
    int w = t >> 6;                        // wave
    int sub = (t >> 5) & 1;                // half-wave
    int p = t & 31;                        // col-pair

    // 0. stage W[b]: 400 float4, fully coalesced (no exp, no seq_len!)
    {
        const float4* src = (const float4*)(W_g + (long)b * (K_SZ * L_SZ));
        float4* dst = (float4*)&W_s[0][0];
        for (int j = t; j < (K_SZ * L_SZ) / 4; j += 256) dst[j] = src[j];
    }
    __syncthreads();                        // B1

    // 1. hp partials: fixed 25 trips, branch-free. Half-wave sub owns rows
    //    l = 8j + 2w + sub; wave reads 512B contiguous per dwordx2.
    {
        float2 acc[K_SZ];
        #pragma unroll
        for (int kk = 0; kk < K_SZ; ++kk) acc[kk] = make_float2(0.f, 0.f);
        int l0 = 2 * w + sub;
        const float2* src = lc2 + l0 * 32 + p;
        #pragma unroll 5
        for (int j = 0; j < 25; ++j) {
            float2 v = src[j * 256];        // row l0+8j, cols 2p,2p+1
            int l = l0 + 8 * j;
            #pragma unroll
            for (int kk = 0; kk < K_SZ; ++kk) {
                float wv = W_s[kk][l];      // 2-addr wave broadcast: free
                acc[kk].x += wv * v.x; acc[kk].y += wv * v.y;
            }
        }
        #pragma unroll
        for (int kk = 0; kk < K_SZ; ++kk) {  // fold sub-rows
            acc[kk].x += __shfl_xor(acc[kk].x, 32, 64);
            acc[kk].y += __shfl_xor(acc[kk].y, 32, 64);
        }
        if (sub == 0) {
            #pragma unroll
            for (int kk = 0; kk < K_SZ; ++kk)
                *(float2*)&hp_part[w][kk][2 * p] = acc[kk];
        }
    }
    __syncthreads();                        // B2

    // 2. hp_s[k] = sum of 4 wave-chunks (W already normalized)
    {
        float2 r = make_float2(0.f, 0.f);
        #pragma unroll
        for (int cc = 0; cc < 4; ++cc) {
            float2 q = *(const float2*)&hp_part[cc][k][2 * g];
            r.x += q.x; r.y += q.y;
        }
        *(float2*)&hp_s[k][2 * g] = r;
        // hp_s[k][*] fully written by warp k; consumed by warp k below.
    }

    // 3. high[k][o] = sum_i hp[k][i]*S[i][o]; squash.  o=2g,2g+1
    float h0 = 0.f, h1 = 0.f;
    {
        const float* sp = S_g + 2 * g;
        #pragma unroll 8
        for (int i = 0; i < DINK; ++i) {
            float pv = hp_s[k][i];                        // same-warp broadcast
            float2 sv = *(const float2*)(sp + i * DOUTK); // L1-hot, coalesced
            h0 += pv * sv.x; h1 += pv * sv.y;
        }
        float nn = h0 * h0 + h1 * h1;
        #pragma unroll
        for (int s = 16; s; s >>= 1) nn += __shfl_xor(nn, s, 32);
        float sc = nn / ((1.0f + nn) * sqrtf(nn + 1e-9f));
        h0 *= sc; h1 *= sc;
    }
    if (WRITE_OUT) {
        float2* ob2 = (float2*)(out + (long)b * (K_SZ * DOUTK) + k * DOUTK);
        ob2[g] = make_float2(h0, h1);
        return;
    }
    *(float2*)&hx_s[k][2 * g] = make_float2(h0, h1);   // same-warp row of ovl

    // 4. hs[k][i] = sum_o high[k][o]*S[i][o] via St (coalesced)
    {
        float s0 = 0.f, s1 = 0.f;
        const float* stp = St_g + 2 * g;
        #pragma unroll 8
        for (int o = 0; o < DOUTK; ++o) {
            float hv = hx_s[k][o];                        // same-warp broadcast
            float2 sv = *(const float2*)(stp + o * DINK); // L1-hot, coalesced
            s0 += hv * sv.x; s1 += hv * sv.y;
        }
        *(float2*)&hs_s[k][2 * g] = make_float2(s0, s1);
    }
    __syncthreads();                        // B3: hs read cross-warp below

    // 5. delta partial[k][l] = sum_i hs[k][i]*lc[l][i]  (ALL l; lc cache-hot)
    if (t < L_SZ) {
        const float4* row4 = (const float4*)(lcb + (long)t * DINK);
        float* pb = partial + (long)b * (K_SZ * L_SZ);
        float acc[K_SZ] = {};
        #pragma unroll 4
        for (int i4 = 0; i4 < 16; ++i4) {
            float4 v = row4[i4];
            #pragma unroll
            for (int kk = 0; kk < K_SZ; ++kk) {
                float4 h = *(const float4*)&hs_s[kk][i4 * 4];  // b128 broadcast
                acc[kk] += v.x * h.x + v.y * h.y + v.z * h.z + v.w * h.w;
            }
        }
        #pragma unroll
        for (int kk = 0; kk < K_SZ; ++kk)
            pb[kk * L_SZ + t] = acc[kk];    // coalesced over t
    }
}

// --------------------------- deterministic two-stage reduce of partials
__global__ __launch_bounds__(256) void k_reduceA(const float* __restrict__ partial,
                                                 float* __restrict__ partial2) {
    __shared__ float red[256];
    int x = blockIdx.x % 50;       // 32-output group
    int y = blockIdx.x / 50;       // 256-batch chunk
    int t = threadIdx.x;
    int i = x * 32 + (t & 31);
    int sub = t >> 5;
    float s = 0.f;
    for (int p = y * 256 + sub; p < (y + 1) * 256; p += 8)
        s += partial[(long)p * (K_SZ * L_SZ) + i];
    red[t] = s;
    __syncthreads();
    for (int step = 4; step >= 1; step >>= 1) {
        if (sub < step) red[t] += red[t + step * 32];
        __syncthreads();
    }
    if (sub == 0) partial2[y * (K_SZ * L_SZ) + i] = red[t];
}

__global__ __launch_bounds__(256) void k_reduceB(const float* __restrict__ partial2,
                                                 float* __restrict__ Bc) {
    int i = blockIdx.x * 256 + threadIdx.x;
    if (i < K_SZ * L_SZ) {
        float s = 0.f;
        #pragma unroll
        for (int y = 0; y < 16; ++y) s += partial2[y * (K_SZ * L_SZ) + i];
        Bc[i] += s;
    }
}

extern "C" void kernel_launch(void* const* d_in, const int* in_sizes, int n_in,
                              void* d_out, int out_size, void* d_ws, size_t ws_size,
                              hipStream_t stream) {
    const float* lc = (const float*)d_in[0];   // [4096,200,64]
    const int*   sl = (const int*)d_in[1];     // [4096,1]
    const float* Bm = (const float*)d_in[2];   // [1,8,200]
    const float* S  = (const float*)d_in[3];   // [64,64]
    float* out = (float*)d_out;                // [4096,8,64]
    float* ws  = (float*)d_ws;

    float* Bc      = ws;                       // 1,600
    float* St      = Bc + 1600;                // 4,096
    float* W       = St + 4096;                // 6,553,600
    float* partial = W + (long)B_SZ * K_SZ * L_SZ;    // 6,553,600
    float* p2      = out;                      // scratch: overwritten by final pass

    k_init<<<23, 256, 0, stream>>>(Bm, S, Bc, St);

    k_soft    <<<B_SZ, 256, 0, stream>>>(sl, Bc, W);
    k_route2<0><<<B_SZ, 256, 0, stream>>>(lc, W, S, St, partial, out);
    k_reduceA <<<800, 256, 0, stream>>>(partial, p2);
    k_reduceB <<<7, 256, 0, stream>>>(p2, Bc);

    k_soft    <<<B_SZ, 256, 0, stream>>>(sl, Bc, W);
    k_route2<0><<<B_SZ, 256, 0, stream>>>(lc, W, S, St, partial, out);
    k_reduceA <<<800, 256, 0, stream>>>(partial, p2);
    k_reduceB <<<7, 256, 0, stream>>>(p2, Bc);

    k_soft    <<<B_SZ, 256, 0, stream>>>(sl, Bc, W);
    k_route2<1><<<B_SZ, 256, 0, stream>>>(lc, W, S, St, partial, out);
}